// Round 7
// baseline (726.853 us; speedup 1.0000x reference)
//
#include <hip/hip_runtime.h>

// Fused GQA attention layer for MI355X (gfx950).
// B=2 S=2048 E=4096 HQ=32 HKV=8 D=128 WINDOW=1024 SOFT_CAP=50 Q_PRE_ATTN=128
//
// R11: QKV GEMM moved to gemm_bk32: 128x256 tile, BK=32, 48KB LDS dbuf ->
//   3 blocks/CU; grid 32x24=768 = 256 CUs x 3 EXACTLY (R6-R10's 256^2 kernel
//   ran 384 blocks @1/CU = 2 rounds for 1.5 rounds of work, 75% packing).
//   Per tile: {8 ds_read | 3 global_load_lds} bar lgkm0 prio1 16xMFMA prio0
//   vmcnt(0) bar — same barrier/MFMA/read density per K-unit as the 8-phase
//   template; prefetch depth 1 tile; 3-way cross-block TLP hides the
//   shallow-prefetch stalls (m114). Out-GEMM stays on proven BK=64 kernel
//   (perfectly packed at 256 blocks). attn/prep unchanged from R10.
//
// Workspace layout (160 MiB, regions reused over time):
//   [0,        33.5M)  xb        -> later vtb
//   [33.5M,    83.9M)  WqkvT     -> later qb|kb
//   [83.9M,   117.4M)  WoT       (persistent)
//   [117.4M,  167.8M)  qkv_raw   -> later attn

typedef unsigned short u16;
typedef unsigned int   u32;
typedef __bf16 bf16x8 __attribute__((ext_vector_type(8)));
typedef float  f32x4  __attribute__((ext_vector_type(4)));
typedef float  f32x16 __attribute__((ext_vector_type(16)));

typedef __attribute__((address_space(1))) void* gas_ptr;
typedef __attribute__((address_space(3))) void* las_ptr;

__device__ __forceinline__ void load_lds16(const void* g, void* l) {
  __builtin_amdgcn_global_load_lds((gas_ptr)g, (las_ptr)l, 16, 0, 0);
}

__device__ __forceinline__ u16 f2bf(float f) {
  u32 u = __builtin_bit_cast(u32, f);
  u += 0x7fffu + ((u >> 16) & 1u);   // RNE
  return (u16)(u >> 16);
}
__device__ __forceinline__ float bf2f(u16 h) {
  u32 u = ((u32)h) << 16;
  return __builtin_bit_cast(float, u);
}
// truncate-pack two fp32 -> bf16 pair (low = a, high = b)
__device__ __forceinline__ u32 pack_trunc(float a, float b) {
  return (__builtin_bit_cast(u32, a) >> 16) | (__builtin_bit_cast(u32, b) & 0xffff0000u);
}

// ---------------------------------------------------------------- cast x
__global__ __launch_bounds__(256) void cast_f32_bf16(const float* __restrict__ src,
                                                     u16* __restrict__ dst) {
  size_t i = ((size_t)blockIdx.x * 256 + threadIdx.x) * 8;
  float4 a = *(const float4*)(src + i);
  float4 b = *(const float4*)(src + i + 4);
  uint4 o;
  o.x = (u32)f2bf(a.x) | ((u32)f2bf(a.y) << 16);
  o.y = (u32)f2bf(a.z) | ((u32)f2bf(a.w) << 16);
  o.z = (u32)f2bf(b.x) | ((u32)f2bf(b.y) << 16);
  o.w = (u32)f2bf(b.z) | ((u32)f2bf(b.w) << 16);
  *(uint4*)(dst + i) = o;
}

// ------------------------------------------------- transpose-cast fp32->bf16
// dst[C][R] = cast(src[R][C]); writes: 8 lanes x uint2 = 64B contiguous/row.
__global__ __launch_bounds__(256) void transpose_cast_f32_bf16(
    const float* __restrict__ src, u16* __restrict__ dst, int R, int C) {
  __shared__ float tile[32][33];
  const int tx = threadIdx.x & 31, ty = threadIdx.x >> 5;
  const int r0 = blockIdx.y * 32, c0 = blockIdx.x * 32;
#pragma unroll
  for (int i = 0; i < 4; ++i)
    tile[ty + i * 8][tx] = src[(size_t)(r0 + ty + i * 8) * C + (c0 + tx)];
  __syncthreads();
  const int cc = threadIdx.x >> 3;       // output row (src col) 0..31
  const int rg = threadIdx.x & 7;        // 4-elem group along r
  uint2 ov;
  ov.x = (u32)f2bf(tile[rg * 4 + 0][cc]) | ((u32)f2bf(tile[rg * 4 + 1][cc]) << 16);
  ov.y = (u32)f2bf(tile[rg * 4 + 2][cc]) | ((u32)f2bf(tile[rg * 4 + 3][cc]) << 16);
  *(uint2*)&dst[(size_t)(c0 + cc) * R + (r0 + rg * 4)] = ov;
}

// ------------------------------------------------- V plane transpose from qkvr
// vtb[plane][d][pos] = qkvr[(b,pos)][(40+h8)*128 + d]; plane = b*8+h8.
__global__ __launch_bounds__(256) void transpose_v(const u16* __restrict__ qkvr,
                                                   u16* __restrict__ vtb) {
  __shared__ u16 tile[32][34];
  const int plane = blockIdx.z;
  const int b = plane >> 3, h8 = plane & 7;
  const u16* s = qkvr + (size_t)(b * 2048) * 6144 + (40 + h8) * 128;
  u16* d = vtb + (size_t)plane * 2048 * 128;
  const int tx = threadIdx.x & 31, ty = threadIdx.x >> 5;
  const int r0 = blockIdx.x * 32, c0 = blockIdx.y * 32;   // r=pos, c=d
#pragma unroll
  for (int i = 0; i < 4; ++i)
    tile[ty + i * 8][tx] = s[(size_t)(r0 + ty + i * 8) * 6144 + (c0 + tx)];
  __syncthreads();
  const int cc = threadIdx.x >> 3;
  const int rg = threadIdx.x & 7;
  uint2 ov;
  ov.x = (u32)tile[rg * 4 + 0][cc] | ((u32)tile[rg * 4 + 1][cc] << 16);
  ov.y = (u32)tile[rg * 4 + 2][cc] | ((u32)tile[rg * 4 + 3][cc] << 16);
  *(uint2*)&d[(size_t)(c0 + cc) * 2048 + (r0 + rg * 4)] = ov;
}

// ---------------------------------------------------------------- GEMM 128x256 BK=32
// C[M][N] = A[M][K] @ Bt[N][K]^T. M%128==0, N%256==0, K%64==0, K pow2-tile
// count assumed (K=4096 -> nt=128). grid = (M/128)*(N/256), grid%8==0.
// LDS (u16 idx): buf b at b*12288; A(128x32) at +0, B(256x32) at +4096.
// Row = 32 u16 (64B); slot = 8 u16 (16B); phys slot = logical ^ (row&3)
// (balanced 8-touches/bank for the frag reads). 3 blocks/CU.
template <int OUT_BF16>
__global__ __launch_bounds__(512, 2) void gemm_bk32(const u16* __restrict__ A,
                                                    const u16* __restrict__ Bt,
                                                    void* __restrict__ Cout,
                                                    int N, int K, int ntx) {
  __shared__ __align__(16) u16 lds[24576];   // 48 KiB
  const int t = threadIdx.x, lane = t & 63, w = t >> 6;
  const int c = lane & 15, q = lane >> 4;
  const int wm = w >> 2, wn = w & 3;         // 2m x 4n waves; 64x64 out/wave

  // bijective XCD swizzle (grid % 8 == 0)
  const int cpx = (int)gridDim.x >> 3;
  const int swz = ((int)blockIdx.x & 7) * cpx + ((int)blockIdx.x >> 3);
  const int bx = swz % ntx, by = swz / ntx;
  const int m0 = by << 7, n0 = bx << 8;

  // staging: 1 load/thread per half (A:128x32=8KB; B0,B1:128x32 each)
  const int rowS = w * 16 + (lane >> 2);
  const u32 colE = (u32)(((lane & 3) ^ (rowS & 3)) * 8);
  const u32 aoff  = (u32)(m0 + rowS) * (u32)K + colE;
  const u32 boff0 = (u32)(n0 + rowS) * (u32)K + colE;
  const u32 boff1 = (u32)(n0 + 128 + rowS) * (u32)K + colE;
  const u32 stW = (u32)w * 512u;

  // frag read bases; row&3 == c&3 for all frags
  const u32 slot = (u32)((q ^ (c & 3)) * 8);
  const u32 aR = (u32)((wm * 64 + c) * 32) + slot;
  const u32 bR = 4096u + (u32)((wn * 64 + c) * 32) + slot;

  f32x4 acc[4][4];
#pragma unroll
  for (int i2 = 0; i2 < 4; ++i2)
#pragma unroll
    for (int j2 = 0; j2 < 4; ++j2) acc[i2][j2] = (f32x4){0.f, 0.f, 0.f, 0.f};

  const int nt = K >> 5;  // 128 for K=4096

#define STG32(bb, kt)                                                     \
  do {                                                                    \
    const u32 b_ = (bb) * 12288u;                                         \
    load_lds16(A + aoff + (u32)(kt) * 32u, &lds[b_ + stW]);               \
    load_lds16(Bt + boff0 + (u32)(kt) * 32u, &lds[b_ + 4096u + stW]);     \
    load_lds16(Bt + boff1 + (u32)(kt) * 32u, &lds[b_ + 8192u + stW]);     \
  } while (0)

#define PH32(bb, ktn)                                                     \
  do {                                                                    \
    const u16* pA = &lds[(bb) * 12288u];                                  \
    bf16x8 af[4], bf[4];                                                  \
    _Pragma("unroll")                                                     \
    for (int m_ = 0; m_ < 4; ++m_) af[m_] = *(const bf16x8*)&pA[aR + m_ * 512u]; \
    _Pragma("unroll")                                                     \
    for (int n_ = 0; n_ < 4; ++n_) bf[n_] = *(const bf16x8*)&pA[bR + n_ * 512u]; \
    STG32((bb) ^ 1, ktn);                                                 \
    __builtin_amdgcn_s_barrier();                                         \
    asm volatile("s_waitcnt lgkmcnt(0)" ::: "memory");                    \
    __builtin_amdgcn_s_setprio(1);                                        \
    _Pragma("unroll")                                                     \
    for (int m_ = 0; m_ < 4; ++m_)                                        \
      _Pragma("unroll")                                                   \
      for (int n_ = 0; n_ < 4; ++n_)                                      \
        acc[m_][n_] = __builtin_amdgcn_mfma_f32_16x16x32_bf16(af[m_], bf[n_], acc[m_][n_], 0, 0, 0); \
    __builtin_amdgcn_s_setprio(0);                                        \
    asm volatile("s_waitcnt vmcnt(0)" ::: "memory");                      \
    __builtin_amdgcn_s_barrier();                                         \
  } while (0)

  // prologue: stage tile0 into buf0
  STG32(0, 0);
  asm volatile("s_waitcnt vmcnt(0)" ::: "memory");
  __builtin_amdgcn_s_barrier();

  for (int i = 0; i < nt; i += 2) {
    PH32(0, i + 1);                          // compute tile i, stage i+1
    int k2 = i + 2;
    if (k2 >= nt) k2 = 0;                    // wrapped tail stage: harmless
    PH32(1, k2);                             // compute tile i+1, stage i+2
  }

#undef STG32
#undef PH32

  const int rb0 = m0 + wm * 64 + q * 4;
  const int cb0 = n0 + wn * 64 + c;
#pragma unroll
  for (int mf = 0; mf < 4; ++mf)
#pragma unroll
    for (int nf = 0; nf < 4; ++nf) {
      const size_t base = (size_t)(rb0 + mf * 16) * N + (cb0 + nf * 16);
#pragma unroll
      for (int r = 0; r < 4; ++r) {
        if (OUT_BF16)
          ((u16*)Cout)[base + (size_t)r * N] = f2bf(acc[mf][nf][r]);
        else
          ((float*)Cout)[base + (size_t)r * N] = acc[mf][nf][r];
      }
    }
}

// ---------------------------------------------------------------- GEMM 256^2 8-phase
// (out-projection only; measured-stable ~113us at 256 blocks = 1.0 rounds)

template <int MB>
__device__ __forceinline__ void mm16(f32x4 (&acc)[8][4], const bf16x8 (&af)[4],
                                     const bf16x8 (&bf)[4]) {
#pragma unroll
  for (int ii = 0; ii < 4; ++ii)
#pragma unroll
    for (int nf = 0; nf < 4; ++nf)
      acc[MB + ii][nf] =
          __builtin_amdgcn_mfma_f32_16x16x32_bf16(af[ii], bf[nf], acc[MB + ii][nf], 0, 0, 0);
}

template <int OUT_BF16>
__global__ __launch_bounds__(512, 2) void gemm256(const u16* __restrict__ A,
                                                  const u16* __restrict__ Bt,
                                                  void* __restrict__ Cout,
                                                  int N, int K, int ntx) {
  __shared__ __align__(16) u16 lds[65536];   // 128 KiB
  const int t = threadIdx.x, lane = t & 63, w = t >> 6;
  const int c = lane & 15, q = lane >> 4;
  const int wm = w >> 2, wn = w & 3;

  const int cpx = (int)gridDim.x >> 3;
  const int swz = ((int)blockIdx.x & 7) * cpx + ((int)blockIdx.x >> 3);
  const int bx = swz % ntx, by = swz / ntx;
  const int m0 = by << 8, n0 = bx << 8;

  u32 aoff[2][2], boff[2][2];
#pragma unroll
  for (int h = 0; h < 2; ++h)
#pragma unroll
    for (int j = 0; j < 2; ++j) {
      const int rowS = w * 16 + j * 8 + (lane >> 3);
      const int colE = ((lane & 7) ^ (rowS & 7)) * 8;
      aoff[h][j] = (u32)(m0 + h * 128 + rowS) * (u32)K + (u32)colE;
      boff[h][j] = (u32)(n0 + h * 128 + rowS) * (u32)K + (u32)colE;
    }
  const u32 stW = (u32)w * 1024u;

  const u32 sl0 = (u32)((q ^ (c & 7)) * 8);
  const u32 aR = (u32)(wm * 8192 + c * 64) + sl0;
  const u32 bR = (u32)(16384 + (wn >> 1) * 8192 + (wn & 1) * 4096 + c * 64) + sl0;

  f32x4 acc[8][4];
#pragma unroll
  for (int i2 = 0; i2 < 8; ++i2)
#pragma unroll
    for (int j2 = 0; j2 < 4; ++j2) acc[i2][j2] = (f32x4){0.f, 0.f, 0.f, 0.f};

  const int nt = K >> 6;

#define STG_A(bb, hh, kt)                                                \
  do {                                                                   \
    u16* d_ = &lds[(bb) * 32768u + (hh) * 8192u + stW];                  \
    load_lds16(A + (aoff[hh][0] + (u32)(kt) * 64u), d_);                 \
    load_lds16(A + (aoff[hh][1] + (u32)(kt) * 64u), d_ + 512);           \
  } while (0)
#define STG_B(bb, hh, kt)                                                \
  do {                                                                   \
    u16* d_ = &lds[(bb) * 32768u + 16384u + (hh) * 8192u + stW];         \
    load_lds16(Bt + (boff[hh][0] + (u32)(kt) * 64u), d_);                \
    load_lds16(Bt + (boff[hh][1] + (u32)(kt) * 64u), d_ + 512);          \
  } while (0)
#define RD4(dst, base)                                                   \
  do {                                                                   \
    const u16* p_ = &lds[(base)];                                        \
    dst[0] = *(const bf16x8*)(p_);                                       \
    dst[1] = *(const bf16x8*)(p_ + 1024);                                \
    dst[2] = *(const bf16x8*)(p_ + 2048);                                \
    dst[3] = *(const bf16x8*)(p_ + 3072);                                \
  } while (0)
#define BAR __builtin_amdgcn_s_barrier()
#define LGKM0 asm volatile("s_waitcnt lgkmcnt(0)" ::: "memory")
#define LGKM8 asm volatile("s_waitcnt lgkmcnt(8)" ::: "memory")
#define VM6 asm volatile("s_waitcnt vmcnt(6)" ::: "memory")
#define PRIO1 __builtin_amdgcn_s_setprio(1)
#define PRIO0 __builtin_amdgcn_s_setprio(0)

  STG_B(0, 0, 0);
  STG_B(0, 1, 0);
  STG_A(0, 0, 0);
  STG_A(0, 1, 0);
  STG_B(1, 0, 1);
  STG_B(1, 1, 1);
  STG_A(1, 0, 1);
  VM6;
  BAR;

  bf16x8 Bf0[4], Bf1[4], Af0[4], Af1[4];

  for (int i = 0; i < (nt >> 1); ++i) {
    const int tb = 2 * i + 1;
    int t2 = 2 * i + 2; if (t2 >= nt) t2 -= nt;
    int t3 = 2 * i + 3; if (t3 >= nt) t3 -= nt;

    RD4(Bf0, bR);
    RD4(Bf1, bR ^ 32u);
    RD4(Af0, aR);
    STG_A(1, 1, tb);
    LGKM8;
    BAR; LGKM0;
    PRIO1; mm16<0>(acc, Af0, Bf0); PRIO0;
    BAR;
    RD4(Af1, aR + 4096u);
    STG_B(0, 0, t2);
    BAR; LGKM0;
    PRIO1; mm16<4>(acc, Af1, Bf0); PRIO0;
    BAR;
    RD4(Af0, aR ^ 32u);
    RD4(Af1, (aR + 4096u) ^ 32u);
    STG_B(0, 1, t2);
    BAR; LGKM0;
    PRIO1; mm16<0>(acc, Af0, Bf1); PRIO0;
    BAR;
    STG_A(0, 0, t2);
    VM6;
    BAR;
    PRIO1; mm16<4>(acc, Af1, Bf1); PRIO0;
    BAR;

    RD4(Bf0, 32768u + bR);
    RD4(Bf1, (32768u + bR) ^ 32u);
    RD4(Af0, 32768u + aR);
    STG_A(0, 1, t2);
    LGKM8;
    BAR; LGKM0;
    PRIO1; mm16<0>(acc, Af0, Bf0); PRIO0;
    BAR;
    RD4(Af1, 32768u + aR + 4096u);
    STG_B(1, 0, t3);
    BAR; LGKM0;
    PRIO1; mm16<4>(acc, Af1, Bf0); PRIO0;
    BAR;
    RD4(Af0, (32768u + aR) ^ 32u);
    RD4(Af1, (32768u + aR + 4096u) ^ 32u);
    STG_B(1, 1, t3);
    BAR; LGKM0;
    PRIO1; mm16<0>(acc, Af0, Bf1); PRIO0;
    BAR;
    STG_A(1, 0, t3);
    VM6;
    BAR;
    PRIO1; mm16<4>(acc, Af1, Bf1); PRIO0;
    BAR;
  }

  asm volatile("s_waitcnt vmcnt(0)" ::: "memory");

#undef STG_A
#undef STG_B
#undef RD4
#undef BAR
#undef LGKM0
#undef LGKM8
#undef VM6
#undef PRIO1
#undef PRIO0

  const int rb0 = m0 + wm * 128 + q * 4;
  const int cb0 = n0 + wn * 64 + c;
#pragma unroll
  for (int mf = 0; mf < 8; ++mf)
#pragma unroll
    for (int nf = 0; nf < 4; ++nf) {
      const size_t base = (size_t)(rb0 + mf * 16) * N + (cb0 + nf * 16);
#pragma unroll
      for (int r = 0; r < 4; ++r) {
        if (OUT_BF16)
          ((u16*)Cout)[base + (size_t)r * N] = f2bf(acc[mf][nf][r]);
        else
          ((float*)Cout)[base + (size_t)r * N] = acc[mf][nf][r];
      }
    }
}

// ---------------------------------------------------------------- qkv postprocess
__global__ __launch_bounds__(256) void qkv_post(const u16* __restrict__ raw,
                                                u16* __restrict__ qb,
                                                u16* __restrict__ kb) {
  const int t = threadIdx.x;
  const int c = t & 15, g = t >> 4;
  const u32 u = (u32)blockIdx.x * 16u + (u32)g;   // u < 163840
  const u32 row = u / 40u;
  const int hh = (int)(u - row * 40u);            // 0..39 (q:0-31, k:32-39)
  const int pos = (int)(row & 2047u);
  const int b = (int)(row >> 11);

  const uint4 rv = *(const uint4*)(raw + (size_t)row * 6144 + hh * 128 + c * 8);
  u32 rw[4] = {rv.x, rv.y, rv.z, rv.w};
  float xs[8];
#pragma unroll
  for (int j = 0; j < 4; ++j) {
    xs[2 * j] = bf2f((u16)(rw[j] & 0xffffu));
    xs[2 * j + 1] = bf2f((u16)(rw[j] >> 16));
  }
  float ss = 0.f;
#pragma unroll
  for (int j = 0; j < 8; ++j) ss += xs[j] * xs[j];
#pragma unroll
  for (int off = 8; off >= 1; off >>= 1) ss += __shfl_xor(ss, off);
  const float rn = rsqrtf(ss * (1.0f / 128.0f) + 1e-6f);

  u32 pw[4];
#pragma unroll
  for (int j = 0; j < 4; ++j) pw[j] = __shfl_xor(rw[j], 8);
  float xp[8];
#pragma unroll
  for (int j = 0; j < 4; ++j) {
    xp[2 * j] = bf2f((u16)(pw[j] & 0xffffu));
    xp[2 * j + 1] = bf2f((u16)(pw[j] >> 16));
  }

  const float sgn = (c < 8) ? -1.0f : 1.0f;
  const int dbase = (c & 7) * 8;
  const float fpos = (float)pos;
  const bool isq = (hh < 32);
  const float sc = (isq ? 0.088388347648318447f : 1.0f) * rn;
  float o[8];
#pragma unroll
  for (int j = 0; j < 8; ++j) {
    const float fr = exp2f(-(float)(dbase + j) * 0.20762050593046f);
    float sn, cs;
    sincosf(fpos * fr, &sn, &cs);
    o[j] = (xs[j] * cs + sgn * xp[j] * sn) * sc;
  }

  uint4 ov;
  ov.x = (u32)f2bf(o[0]) | ((u32)f2bf(o[1]) << 16);
  ov.y = (u32)f2bf(o[2]) | ((u32)f2bf(o[3]) << 16);
  ov.z = (u32)f2bf(o[4]) | ((u32)f2bf(o[5]) << 16);
  ov.w = (u32)f2bf(o[6]) | ((u32)f2bf(o[7]) << 16);
  u16* dst = isq ? (qb + ((size_t)((b * 32 + hh) * 2048 + pos)) * 128)
                 : (kb + ((size_t)((b * 8 + (hh - 32)) * 2048 + pos)) * 128);
  *(uint4*)(dst + c * 8) = ov;
}

// ---------------------------------------------------------------- flash attention
// R10 structure (measured == R9 best): 32x32x16 MFMA; block = (b,hq,64 q);
// 4 waves split 2x2; Q in regs; P via shared swizzled LDS; 3 barriers/tile.
__global__ __launch_bounds__(256, 4) void attn_fwd(const u16* __restrict__ qb,
                                                   const u16* __restrict__ kb,
                                                   const u16* __restrict__ vtb,
                                                   u16* __restrict__ attn) {
  __shared__ __align__(16) u16 Ks[64 * 128];   // [key][d], slot^=(key&15)
  __shared__ __align__(16) u16 VTs[128 * 64];  // [d][key], slot^=(d&7)
  __shared__ __align__(16) u16 Ps[64 * 64];    // [q][key], slot^=(q&7)
  __shared__ float Ls[2][64];                  // per-kh lsum partials

  const int t = threadIdx.x, lane = t & 63, w = t >> 6;
  const int l31 = lane & 31, h5 = lane >> 5;
  const int kh = w >> 1, qh = w & 1;           // QK role; PV: dh = kh
  const int q0 = blockIdx.x * 64;
  const int bh = blockIdx.y;
  const int b = bh >> 5, hq = bh & 31;
  const int kvp = b * 8 + (hq >> 2);
  const u16* qp = qb + (size_t)bh * (2048 * 128);
  const u16* kp = kb + (size_t)kvp * (2048 * 128);
  const u16* vp = vtb + (size_t)kvp * (128 * 2048);

  bf16x8 qf[8];
  {
    const u16* qrow = qp + (size_t)(q0 + qh * 32 + l31) * 128 + h5 * 8;
#pragma unroll
    for (int kst = 0; kst < 8; ++kst) qf[kst] = *(const bf16x8*)(qrow + kst * 16);
  }

  f32x16 oacc[2];
#pragma unroll
  for (int dc = 0; dc < 2; ++dc)
#pragma unroll
    for (int r = 0; r < 16; ++r) oacc[dc][r] = 0.0f;
  float lsum = 0.0f;

  const int iq = q0 + qh * 32 + l31;

  int t0 = q0 - 1023;
  if (t0 < 0) t0 = 0;
  t0 = (t0 >> 6) << 6;

  for (int kv0 = t0; kv0 <= q0; kv0 += 64) {
    __syncthreads();
    {
      const int row_in = lane >> 4, ch = lane & 15;
#pragma unroll
      for (int i = 0; i < 4; ++i) {
        const int row = w * 4 + i * 16 + row_in;
        const int g = ch ^ (row & 15);
        load_lds16(kp + (size_t)(kv0 + row) * 128 + g * 8, &Ks[(w * 4 + i * 16) * 128]);
      }
      const int drow = lane >> 3, ch8 = lane & 7;
#pragma unroll
      for (int i = 0; i < 4; ++i) {
        const int dd = w * 8 + i * 32 + drow;
        const int g = ch8 ^ (dd & 7);
        load_lds16(vp + (size_t)dd * 2048 + kv0 + g * 8, &VTs[(w * 8 + i * 32) * 64]);
      }
    }
    __syncthreads();

    f32x16 sacc;
#pragma unroll
    for (int r = 0; r < 16; ++r) sacc[r] = 0.0f;
    {
      const int key = kh * 32 + l31;
      const u16* krow = &Ks[key * 128];
      const int s15 = key & 15;
#pragma unroll
      for (int kst = 0; kst < 8; ++kst) {
        const int phys = (kst * 2 + h5) ^ s15;
        const bf16x8 af = *(const bf16x8*)(krow + phys * 8);
        sacc = __builtin_amdgcn_mfma_f32_32x32x16_bf16(af, qf[kst], sacc, 0, 0, 0);
      }
    }

    const bool need_mask = (kv0 == q0) || (q0 - kv0 >= 961);
    float pv[16];
#pragma unroll
    for (int r = 0; r < 16; ++r) {
      const float s = sacc[r];
      const float u = s * s;
      const float cap = s * (1.0f + u * (-1.3333333e-4f + u * 2.1333333e-8f));
      pv[r] = __expf(cap);
    }
    if (need_mask) {
#pragma unroll
      for (int r = 0; r < 16; ++r) {
        const int key = kv0 + kh * 32 + (r & 3) + 8 * (r >> 2) + 4 * h5;
        if (!((key <= iq) && (iq - key < 1024))) pv[r] = 0.0f;
      }
    }
#pragma unroll
    for (int r = 0; r < 16; ++r) lsum += pv[r];

    {
      const int qrow = qh * 32 + l31;
      u16* prow = &Ps[qrow * 64];
      const int s7 = l31 & 7;
#pragma unroll
      for (int g = 0; g < 4; ++g) {
        uint2 pk;
        pk.x = pack_trunc(pv[4 * g + 0], pv[4 * g + 1]);
        pk.y = pack_trunc(pv[4 * g + 2], pv[4 * g + 3]);
        const int phys = (kh * 4 + g) ^ s7;
        *(uint2*)(prow + phys * 8 + h5 * 4) = pk;
      }
    }
    __syncthreads();

    {
      const u16* prow = &Ps[(qh * 32 + l31) * 64];
      const int s7 = l31 & 7;
#pragma unroll
      for (int kst = 0; kst < 4; ++kst) {
        const int physp = (kst * 2 + h5) ^ s7;
        const bf16x8 pf = *(const bf16x8*)(prow + physp * 8);
#pragma unroll
        for (int dc = 0; dc < 2; ++dc) {
          const int drow = kh * 64 + dc * 32 + l31;
          const int physv = (kst * 2 + h5) ^ (drow & 7);
          const bf16x8 vf = *(const bf16x8*)&VTs[drow * 64 + physv * 8];
          oacc[dc] = __builtin_amdgcn_mfma_f32_32x32x16_bf16(pf, vf, oacc[dc], 0, 0, 0);
        }
      }
    }
  }

  float lt = lsum + __shfl_xor(lsum, 32);
  if (lane < 32) Ls[kh][qh * 32 + lane] = lt;
  __syncthreads();

  float rl16[16];
#pragma unroll
  for (int r = 0; r < 16; ++r) {
    const int qi = qh * 32 + (r & 3) + 8 * (r >> 2) + 4 * h5;
    rl16[r] = __builtin_amdgcn_rcpf(Ls[0][qi] + Ls[1][qi]);
  }

  const size_t ob = ((size_t)(b * 2048 + q0 + qh * 32)) * 4096 + hq * 128 + kh * 64;
#pragma unroll
  for (int dc = 0; dc < 2; ++dc)
#pragma unroll
    for (int r = 0; r < 16; ++r) {
      const int qi = (r & 3) + 8 * (r >> 2) + 4 * h5;
      attn[ob + (size_t)qi * 4096 + dc * 32 + l31] = f2bf(oacc[dc][r] * rl16[r]);
    }
}

// ---------------------------------------------------------------- launch
extern "C" void kernel_launch(void* const* d_in, const int* in_sizes, int n_in,
                              void* d_out, int out_size, void* d_ws, size_t ws_size,
                              hipStream_t stream) {
  (void)in_sizes; (void)n_in; (void)out_size; (void)ws_size;
  const float* x  = (const float*)d_in[0];
  const float* Wq = (const float*)d_in[1];
  const float* Wk = (const float*)d_in[2];
  const float* Wv = (const float*)d_in[3];
  const float* Wo = (const float*)d_in[4];
  float* out = (float*)d_out;
  char* ws = (char*)d_ws;

  u16* xb    = (u16*)(ws + 0);
  u16* vtb   = (u16*)(ws + 0);
  u16* WqkvT = (u16*)(ws + 33554432ULL);
  u16* qb    = (u16*)(ws + 33554432ULL);
  u16* kb    = (u16*)(ws + 67108864ULL);
  u16* WoT   = (u16*)(ws + 83886080ULL);
  u16* qkvr  = (u16*)(ws + 117440512ULL);
  u16* attnb = (u16*)(ws + 117440512ULL);

  cast_f32_bf16<<<8192, 256, 0, stream>>>(x, xb);
  transpose_cast_f32_bf16<<<dim3(128, 128), 256, 0, stream>>>(Wq, WqkvT, 4096, 4096);
  transpose_cast_f32_bf16<<<dim3(32, 128), 256, 0, stream>>>(Wk, WqkvT + (size_t)4096 * 4096, 4096, 1024);
  transpose_cast_f32_bf16<<<dim3(32, 128), 256, 0, stream>>>(Wv, WqkvT + (size_t)5120 * 4096, 4096, 1024);
  transpose_cast_f32_bf16<<<dim3(128, 128), 256, 0, stream>>>(Wo, WoT, 4096, 4096);

  // QKV: M=4096 (32 tiles of 128), N=6144 (24 tiles of 256) -> 768 blocks
  // = 256 CUs x 3 blocks/CU exactly (48KB LDS).
  gemm_bk32<1><<<dim3(768), 512, 0, stream>>>(xb, WqkvT, (void*)qkvr, 6144, 4096, 24);
  qkv_post<<<10240, 256, 0, stream>>>(qkvr, qb, kb);
  transpose_v<<<dim3(64, 4, 16), 256, 0, stream>>>(qkvr, vtb);
  attn_fwd<<<dim3(32, 64), 256, 0, stream>>>(qb, kb, vtb, attnb);
  // Out: M=4096, N=4096, K=4096 -> 16x16 = 256 tiles (1.0 rounds, BK=64)
  gemm256<0><<<dim3(256), 512, 0, stream>>>(attnb, WoT, (void*)out, 4096, 4096, 16);
}